// Round 2
// baseline (479.308 us; speedup 1.0000x reference)
//
#include <hip/hip_runtime.h>
#include <hip/hip_bf16.h>
#include <cstdint>

#define N_NODES 100000
#define N_EDGES 1600000
#define N_GRAPHS 64
#define IN_DIM 256
#define HD1 128
#define HD2 256
#define OUT_DIM 512

// CSR-build radix partition parameters
#define NBUCK 196          // ceil(100000/512) buckets of 512 dst nodes
#define NBLK  196          // edge-chunk blocks
#define EPB   8192         // edges per block (NBLK*EPB >= N_EDGES)

typedef __bf16 bf16x8 __attribute__((ext_vector_type(8)));
typedef float f32x4 __attribute__((ext_vector_type(4)));

static __device__ __forceinline__ float bflo(uint32_t v) { return __uint_as_float(v << 16); }
static __device__ __forceinline__ float bfhi(uint32_t v) { return __uint_as_float(v & 0xffff0000u); }
static __device__ __forceinline__ uint32_t f2bf_bits(float f) {
    uint32_t u = __float_as_uint(f);
    return (u + 0x7fffu + ((u >> 16) & 1u)) >> 16;   // RNE
}
static __device__ __forceinline__ uint32_t packbf(float a, float b) {
    return f2bf_bits(a) | (f2bf_bits(b) << 16);
}
static __device__ __forceinline__ float bf2f(uint16_t b) { return __uint_as_float(((uint32_t)b) << 16); }

// ---------------- runtime dtype probe ----------------
__global__ void k_probe(const uint32_t* __restrict__ xw, const int* __restrict__ ei,
                        int* __restrict__ flags) {
    if (threadIdx.x != 0 || blockIdx.x != 0) return;
    int mid = 0;
    for (int i = 0; i < 64; i++) {
        uint32_t f = (xw[i] >> 23) & 0xFF;
        if (f >= 64 && f < 200) mid++;
    }
    flags[0] = (mid < 32) ? 1 : 0;                  // bf16 vs f32
    int nz = 0;
    for (int i = 0; i < 64; i++) if (ei[2 * i + 1] != 0) nz++;
    flags[1] = (nz == 0) ? 1 : 0;                   // int64 vs int32
}

static __device__ __forceinline__ int ld_idx(const int* p, int i, int sh) { return p[i << sh]; }
static __device__ __forceinline__ float ld_f(const void* p, int i, int isbf) {
    return isbf ? bf2f(((const uint16_t*)p)[i]) : ((const float*)p)[i];
}

// ---------------- fused weight/bias canonicalization (bf16, transposed) ----------------
__global__ __launch_bounds__(256) void k_prep(const void* __restrict__ W1, const void* __restrict__ W2,
                                              const void* __restrict__ fcW, const void* __restrict__ b1,
                                              const void* __restrict__ b2, const void* __restrict__ fcb,
                                              uint16_t* __restrict__ W1T, uint16_t* __restrict__ W2T,
                                              uint16_t* __restrict__ fcWc, uint16_t* __restrict__ bc1,
                                              uint16_t* __restrict__ bc2, uint16_t* __restrict__ fcbc,
                                              const int* __restrict__ flags) {
    int i = blockIdx.x * 256 + threadIdx.x;
    int isbf = flags[0];
    if (i < 32768) {                                   // W1T[n][k] = W1[k][n], [128][256]
        int n = i / IN_DIM, k = i % IN_DIM;
        W1T[i] = (uint16_t)f2bf_bits(ld_f(W1, k * HD1 + n, isbf));
    } else if (i < 65536) {                            // W2T[n][k] = W2[k][n], [256][128]
        int j = i - 32768;
        int n = j / HD1, k = j % HD1;
        W2T[j] = (uint16_t)f2bf_bits(ld_f(W2, k * HD2 + n, isbf));
    } else if (i < 196608) {
        int j = i - 65536;
        fcWc[j] = (uint16_t)f2bf_bits(ld_f(fcW, j, isbf));
    } else if (i < 196736) {
        bc1[i - 196608] = (uint16_t)f2bf_bits(ld_f(b1, i - 196608, isbf));
    } else if (i < 196992) {
        bc2[i - 196736] = (uint16_t)f2bf_bits(ld_f(b2, i - 196736, isbf));
    } else if (i < 197504) {
        fcbc[i - 196992] = (uint16_t)f2bf_bits(ld_f(fcb, i - 196992, isbf));
    }
}

// ---------------- CSR build: atomic-free radix partition by dst bucket ----------------

__global__ __launch_bounds__(256) void k_hist(const int* __restrict__ ei, int* __restrict__ bh,
                                              const int* __restrict__ flags) {
    __shared__ int h[NBUCK];
    int t = threadIdx.x, blk = blockIdx.x;
    if (t < NBUCK) h[t] = 0;
    __syncthreads();
    int sh = flags[1];
    int base = blk * EPB;
#pragma unroll
    for (int k = 0; k < EPB / 256; k++) {
        int e = base + k * 256 + t;
        if (e < N_EDGES) atomicAdd(&h[ld_idx(ei, N_EDGES + e, sh) >> 9], 1);
    }
    __syncthreads();
    if (t < NBUCK) bh[blk * NBUCK + t] = h[t];
}

__global__ __launch_bounds__(256) void k_colscan(const int* __restrict__ bh, int* __restrict__ bhoff,
                                                 int* __restrict__ bucket_cnt) {
    __shared__ int s[256];
    int b = blockIdx.x, t = threadIdx.x;
    int v = (t < NBLK) ? bh[t * NBUCK + b] : 0;
    s[t] = v; __syncthreads();
    for (int off = 1; off < 256; off <<= 1) {
        int x = (t >= off) ? s[t - off] : 0;
        __syncthreads();
        s[t] += x;
        __syncthreads();
    }
    if (t < NBLK) bhoff[t * NBUCK + b] = s[t] - v;    // exclusive within bucket
    if (t == 255) bucket_cnt[b] = s[255];
}

__global__ __launch_bounds__(256) void k_bscan(const int* __restrict__ bucket_cnt,
                                               int* __restrict__ bucket_base,
                                               int* __restrict__ row_ptr) {
    __shared__ int s[256];
    int t = threadIdx.x;
    int v = (t < NBUCK) ? bucket_cnt[t] : 0;
    s[t] = v; __syncthreads();
    for (int off = 1; off < 256; off <<= 1) {
        int x = (t >= off) ? s[t - off] : 0;
        __syncthreads();
        s[t] += x;
        __syncthreads();
    }
    if (t < NBUCK) bucket_base[t] = s[t] - v;
    if (t == NBUCK - 1) { bucket_base[NBUCK] = s[t]; row_ptr[N_NODES] = s[t]; }
}

__global__ __launch_bounds__(256) void k_part(const int* __restrict__ ei,
                                              const int* __restrict__ bucket_base,
                                              const int* __restrict__ bhoff,
                                              int* __restrict__ tmp,
                                              const int* __restrict__ flags) {
    __shared__ int cur[NBUCK];
    int t = threadIdx.x, blk = blockIdx.x;
    if (t < NBUCK) cur[t] = bucket_base[t] + bhoff[blk * NBUCK + t];
    __syncthreads();
    int sh = flags[1];
    int base = blk * EPB;
#pragma unroll
    for (int k = 0; k < EPB / 256; k++) {
        int e = base + k * 256 + t;
        if (e < N_EDGES) {
            int s = ld_idx(ei, e, sh), d = ld_idx(ei, N_EDGES + e, sh);
            int pos = atomicAdd(&cur[d >> 9], 1);
            tmp[pos] = (s << 9) | (d & 511);          // s<2^17 -> 26-bit key
        }
    }
}

__global__ __launch_bounds__(256) void k_bsort(const int* __restrict__ tmp,
                                               const int* __restrict__ bucket_base,
                                               int* __restrict__ csr_src,
                                               int* __restrict__ row_ptr,
                                               float* __restrict__ dinv) {
    __shared__ int h[512], a[512], c[512];
    int b = blockIdx.x, t = threadIdx.x;
    int beg = bucket_base[b], end = bucket_base[b + 1];
    h[t] = 0; h[t + 256] = 0;
    __syncthreads();
    for (int i = beg + t; i < end; i += 256) atomicAdd(&h[tmp[i] & 511], 1);
    __syncthreads();
    a[t] = h[t]; a[t + 256] = h[t + 256];
    __syncthreads();
    for (int off = 1; off < 512; off <<= 1) {
        int x0 = (t >= off) ? a[t - off] : 0;
        int x1 = ((t + 256) >= off) ? a[t + 256 - off] : 0;
        __syncthreads();
        a[t] += x0; a[t + 256] += x1;
        __syncthreads();
    }
#pragma unroll
    for (int u = 0; u < 2; u++) {
        int i = t + u * 256;
        int node = (b << 9) + i;
        int ex = a[i] - h[i];
        if (node < N_NODES) {
            row_ptr[node] = beg + ex;
            dinv[node] = rsqrtf((float)(h[i] + 1));   // +1 self-loop
        }
        c[i] = ex;
    }
    __syncthreads();
    for (int i = beg + t; i < end; i += 256) {
        int e = tmp[i];
        int pos = atomicAdd(&c[e & 511], 1);
        csr_src[beg + pos] = e >> 9;
    }
}

// ---------------- per-graph node counts ----------------
#define GCNT_CHUNK 8
__global__ __launch_bounds__(256) void k_gcnt(const int* __restrict__ bat, int* __restrict__ gcnt,
                                              const int* __restrict__ flags) {
    __shared__ int h[N_GRAPHS];
    int t = threadIdx.x;
    if (t < N_GRAPHS) h[t] = 0;
    __syncthreads();
    int sh = flags[1];
    int base = (blockIdx.x * 256 + t) * GCNT_CHUNK;
    int cur = -1, run = 0;
#pragma unroll
    for (int u = 0; u < GCNT_CHUNK; u++) {
        int i = base + u;
        if (i < N_NODES) {
            int g = ld_idx(bat, i, sh);
            if (g == cur) run++;
            else { if (run) atomicAdd(&h[cur], run); cur = g; run = 1; }
        }
    }
    if (run) atomicAdd(&h[cur], run);
    __syncthreads();
    if (t < N_GRAPHS) { int v = h[t]; if (v) atomicAdd(&gcnt[t], v); }
}

// ---------------- GEMM-1: Y1[M,128] = X[M,256] @ W1 ----------------
// Register-resident B: each wave owns 32 rows x 32 cols; its B slice
// (32 cols x 256 K = 16KB/64 lanes = 64 VGPR) is preloaded ONCE before the
// K-loop. Inner loop = 2 independent A-loads + 4 MFMA, fully unrolled ->
// compiler can run A-loads many deep (MLP). Grid 3125 blocks, 4 waves
// sharing one 16KB A-tile via L1. No LDS, no barriers.

__global__ __launch_bounds__(256, 4) void k_gemm1(const void* __restrict__ Ain,
                                                  const uint16_t* __restrict__ BT,  // [128][256] bf16
                                                  uint16_t* __restrict__ C,
                                                  const int* __restrict__ flags) {
    const int K = IN_DIM, N = HD1;
    int isbf = flags[0];
    int t = threadIdx.x;
    int wave = t >> 6, lane = t & 63;
    int quad = lane >> 4, l16 = lane & 15;
    int m0 = blockIdx.x * 32;                         // 3125 * 32 == 100000, no tail
    int n0 = wave * 32;                               // wave's column group

    // B slice for this wave: [nt][ks] fragment
    bf16x8 Bf[2][8];
#pragma unroll
    for (int nt = 0; nt < 2; nt++)
#pragma unroll
        for (int ks = 0; ks < 8; ks++)
            Bf[nt][ks] = *(const bf16x8*)(BT + (n0 + nt * 16 + l16) * K + ks * 32 + quad * 8);

    f32x4 acc[2][2];
#pragma unroll
    for (int a = 0; a < 2; a++)
#pragma unroll
        for (int b = 0; b < 2; b++) acc[a][b] = f32x4{0.f, 0.f, 0.f, 0.f};

    int arow[2] = { m0 + l16, m0 + 16 + l16 };

#pragma unroll
    for (int ks = 0; ks < 8; ks++) {                  // K = 8 x 32
        int kc = ks * 32 + quad * 8;
        bf16x8 af[2];
#pragma unroll
        for (int mt = 0; mt < 2; mt++) {
            int off = arow[mt] * K + kc;
            if (isbf) {
                af[mt] = *(const bf16x8*)((const uint16_t*)Ain + off);
            } else {
                const float* p = (const float*)Ain + off;
                f32x4 f0 = *(const f32x4*)p, f1 = *(const f32x4*)(p + 4);
                union { uint16_t u[8]; bf16x8 v; } r;
#pragma unroll
                for (int j = 0; j < 4; j++) {
                    r.u[j]     = (uint16_t)f2bf_bits(f0[j]);
                    r.u[4 + j] = (uint16_t)f2bf_bits(f1[j]);
                }
                af[mt] = r.v;
            }
        }
#pragma unroll
        for (int mt = 0; mt < 2; mt++)
#pragma unroll
            for (int nt = 0; nt < 2; nt++)
                acc[mt][nt] = __builtin_amdgcn_mfma_f32_16x16x32_bf16(af[mt], Bf[nt][ks], acc[mt][nt], 0, 0, 0);
    }

#pragma unroll
    for (int mt = 0; mt < 2; mt++)
#pragma unroll
        for (int reg = 0; reg < 4; reg++) {
            int row = m0 + mt * 16 + quad * 4 + reg;  // C/D: col=lane&15, row=quad*4+reg
#pragma unroll
            for (int nt = 0; nt < 2; nt++)
                C[row * N + n0 + nt * 16 + l16] = (uint16_t)f2bf_bits(acc[mt][nt][reg]);
        }
}

// ---------------- aggregation (wave-cooperative; readlane broadcast, 16-deep gather) ----------------
// out[d] = dinv[d] * (sum_src dinv[s]*Y[s] + dinv[d]*Y[d]) [+bias, relu]
// v_readlane (uniform index) -> SGPR src + scalar addressing: no ds_bpermute LDS-pipe traffic.

template <int WITH_BIAS_RELU>
__global__ __launch_bounds__(256) void k_agg(const uint16_t* __restrict__ Yin, uint16_t* __restrict__ Yout,
                                             const int* __restrict__ row_ptr, const int* __restrict__ csr_src,
                                             const float* __restrict__ dinv, const uint16_t* __restrict__ bias) {
    int node = blockIdx.x * 4 + (threadIdx.x >> 6);
    int l = threadIdx.x & 63;
    const uint32_t* Y32 = (const uint32_t*)Yin;

    float wd = dinv[node];
    uint32_t v = Y32[(size_t)node * 64 + l];
    float a0 = wd * bflo(v), a1 = wd * bfhi(v);

    int e0 = row_ptr[node], e1 = row_ptr[node + 1];
    for (int cb = e0; cb < e1; cb += 64) {
        int cnt = e1 - cb; if (cnt > 64) cnt = 64;
        // lane-parallel prefetch of indices + weights (1 coalesced load + 1 gather)
        int my_src = 0; uint32_t my_w = 0;            // lanes >= cnt: w=0 -> contribute 0, read row 0
        if (l < cnt) { my_src = csr_src[cb + l]; my_w = __float_as_uint(dinv[my_src]); }
        int rounds = (cnt + 15) >> 4;
        for (int r = 0; r < rounds; r++) {
            int jb = r * 16;
            uint32_t vv[16];
#pragma unroll
            for (int t = 0; t < 16; t++) {
                int s = __builtin_amdgcn_readlane(my_src, jb + t);   // SGPR: scalar addr math
                vv[t] = Y32[(size_t)s * 64 + l];
            }
#pragma unroll
            for (int t = 0; t < 16; t++) {
                float w = __uint_as_float(__builtin_amdgcn_readlane(my_w, jb + t));
                a0 += w * bflo(vv[t]);
                a1 += w * bfhi(vv[t]);
            }
        }
    }
    a0 *= wd; a1 *= wd;
    if (WITH_BIAS_RELU) {
        a0 = fmaxf(a0 + bf2f(bias[2 * l]), 0.f);
        a1 = fmaxf(a1 + bf2f(bias[2 * l + 1]), 0.f);
    }
    ((uint32_t*)Yout)[(size_t)node * 64 + l] = packbf(a0, a1);
}

// ---------------- GEMM-2 + fused bias/relu/pool: pooled[g] += relu(Z@W2 + b2) ----------------
// Register-resident B, same structure as k_gemm1: 512 threads = 8 column-group
// waves covering all 256 output cols; block = 32 rows, A-tile (8KB) read once.

__global__ __launch_bounds__(512, 4) void k_gemm2_pool(const uint16_t* __restrict__ A,   // Zb [M][128]
                                                       const uint16_t* __restrict__ BT,  // W2T [256][128]
                                                       const uint16_t* __restrict__ bias,// bc2 [256]
                                                       const int* __restrict__ bat,
                                                       const int* __restrict__ flags,
                                                       float* __restrict__ pooled) {
    const int K = HD1;
    int t = threadIdx.x;
    int wave = t >> 6, lane = t & 63;
    int quad = lane >> 4, l16 = lane & 15;
    int m0 = blockIdx.x * 32;                         // 3125 * 32 == 100000
    int n0 = wave * 32;                               // 8 waves x 32 cols = 256

    bf16x8 Bf[2][4];
#pragma unroll
    for (int nt = 0; nt < 2; nt++)
#pragma unroll
        for (int ks = 0; ks < 4; ks++)
            Bf[nt][ks] = *(const bf16x8*)(BT + (n0 + nt * 16 + l16) * K + ks * 32 + quad * 8);

    f32x4 acc[2][2];
#pragma unroll
    for (int a = 0; a < 2; a++)
#pragma unroll
        for (int b = 0; b < 2; b++) acc[a][b] = f32x4{0.f, 0.f, 0.f, 0.f};

    int arow[2] = { m0 + l16, m0 + 16 + l16 };

#pragma unroll
    for (int ks = 0; ks < 4; ks++) {                  // K = 4 x 32
        int kc = ks * 32 + quad * 8;
        bf16x8 af[2];
#pragma unroll
        for (int mt = 0; mt < 2; mt++)
            af[mt] = *(const bf16x8*)(A + arow[mt] * K + kc);
#pragma unroll
        for (int mt = 0; mt < 2; mt++)
#pragma unroll
            for (int nt = 0; nt < 2; nt++)
                acc[mt][nt] = __builtin_amdgcn_mfma_f32_16x16x32_bf16(af[mt], Bf[nt][ks], acc[mt][nt], 0, 0, 0);
    }

    int sh = flags[1];
    float bv[2];
#pragma unroll
    for (int nt = 0; nt < 2; nt++) bv[nt] = bf2f(bias[n0 + nt * 16 + l16]);

    // rows m0..m0+31; graph-uniform fast path
    int gfirst = ld_idx(bat, m0, sh);
    int glast  = ld_idx(bat, m0 + 31, sh);
    if (gfirst == glast) {
#pragma unroll
        for (int nt = 0; nt < 2; nt++) {
            float s = 0.f;
#pragma unroll
            for (int mt = 0; mt < 2; mt++)
#pragma unroll
                for (int reg = 0; reg < 4; reg++)
                    s += fmaxf(acc[mt][nt][reg] + bv[nt], 0.f);
            s += __shfl_xor(s, 16);
            s += __shfl_xor(s, 32);
            if (quad == 0)
                atomicAdd(&pooled[gfirst * HD2 + n0 + nt * 16 + l16], s);
        }
    } else {
#pragma unroll
        for (int mt = 0; mt < 2; mt++) {
            int rb = m0 + mt * 16 + quad * 4;
#pragma unroll
            for (int reg = 0; reg < 4; reg++) {
                int g = ld_idx(bat, rb + reg, sh);
#pragma unroll
                for (int nt = 0; nt < 2; nt++)
                    atomicAdd(&pooled[g * HD2 + n0 + nt * 16 + l16],
                              fmaxf(acc[mt][nt][reg] + bv[nt], 0.f));
            }
        }
    }
}

// ---------------- final FC: out = relu(mean @ fcW + fcb), dual-dtype out ----------------

__global__ __launch_bounds__(512) void k_final(const float* __restrict__ pooled, const int* __restrict__ gcnt,
                                               const uint16_t* __restrict__ fcWc, const uint16_t* __restrict__ fcbc,
                                               void* __restrict__ out, const int* __restrict__ flags) {
    __shared__ float pm[HD2];
    int g = blockIdx.x, t = threadIdx.x;
    if (t < HD2) pm[t] = pooled[g * HD2 + t] / fmaxf((float)gcnt[g], 1.0f);
    __syncthreads();
    float acc = bf2f(fcbc[t]);
    for (int k = 0; k < HD2; k++) acc = fmaf(pm[k], bf2f(fcWc[k * OUT_DIM + t]), acc);
    acc = fmaxf(acc, 0.f);
    if (flags[0]) ((uint16_t*)out)[g * OUT_DIM + t] = (uint16_t)f2bf_bits(acc);
    else          ((float*)out)[g * OUT_DIM + t] = acc;
}

// ---------------- launcher ----------------

extern "C" void kernel_launch(void* const* d_in, const int* in_sizes, int n_in,
                              void* d_out, int out_size, void* d_ws, size_t ws_size,
                              hipStream_t stream) {
    const void* x   = d_in[0];               // [100000,256] bf16 or f32
    const int*  ei  = (const int*)d_in[1];   // [2,1600000] int32 or int64
    const int*  bat = (const int*)d_in[2];   // [100000]
    const void* W1  = d_in[3];               // [256,128]
    const void* b1  = d_in[4];               // [128]
    const void* W2  = d_in[5];               // [128,256]
    const void* b2  = d_in[6];               // [256]
    const void* fcW = d_in[7];               // [256,512]
    const void* fcb = d_in[8];               // [512]

    char* ws = (char*)d_ws;
    size_t off = 0;
    auto alloc = [&](size_t bytes) -> void* {
        void* p = ws + off;
        off += (bytes + 255) & ~(size_t)255;
        return p;
    };
    uint16_t* buf0 = (uint16_t*)alloc((size_t)N_NODES * HD1 * 2);   // Y1, later Zb
    uint16_t* Hb   = (uint16_t*)alloc((size_t)N_NODES * HD1 * 2);
    int*   row_ptr = (int*)alloc((N_NODES + 1) * 4);
    int*   csr_src = (int*)alloc((size_t)N_EDGES * 4);
    int*   tmp     = (int*)alloc((size_t)N_EDGES * 4);
    int*   bh      = (int*)alloc(NBLK * NBUCK * 4);
    int*   bhoff   = (int*)alloc(NBLK * NBUCK * 4);
    int*   bucket_cnt  = (int*)alloc(NBUCK * 4);
    int*   bucket_base = (int*)alloc((NBUCK + 1) * 4);
    float* dinv    = (float*)alloc(N_NODES * 4);
    int*   gcnt    = (int*)alloc(N_GRAPHS * 4);
    float* pooled  = (float*)alloc(N_GRAPHS * HD2 * 4);
    uint16_t* W1T  = (uint16_t*)alloc(IN_DIM * HD1 * 2);
    uint16_t* W2T  = (uint16_t*)alloc(HD1 * HD2 * 2);
    uint16_t* bc1  = (uint16_t*)alloc(HD1 * 2);
    uint16_t* bc2  = (uint16_t*)alloc(HD2 * 2);
    uint16_t* fcWc = (uint16_t*)alloc(HD2 * OUT_DIM * 2);
    uint16_t* fcbc = (uint16_t*)alloc(OUT_DIM * 2);
    int*   flags   = (int*)alloc(64 * 4);

    uint16_t* Y1 = buf0;
    uint16_t* Zb = buf0;   // Y1 dead after agg-1

    hipMemsetAsync(gcnt, 0, N_GRAPHS * 4, stream);
    hipMemsetAsync(pooled, 0, N_GRAPHS * HD2 * 4, stream);

    k_probe<<<1, 64, 0, stream>>>((const uint32_t*)x, ei, flags);

    // canonicalize weights/biases to bf16 (one fused kernel)
    k_prep<<<(197504 + 255) / 256, 256, 0, stream>>>(W1, W2, fcW, b1, b2, fcb,
                                                     W1T, W2T, fcWc, bc1, bc2, fcbc, flags);

    // CSR build: hist -> colscan -> bscan -> part -> bucket sort (no global atomics)
    k_hist<<<NBLK, 256, 0, stream>>>(ei, bh, flags);
    k_colscan<<<NBUCK, 256, 0, stream>>>(bh, bhoff, bucket_cnt);
    k_bscan<<<1, 256, 0, stream>>>(bucket_cnt, bucket_base, row_ptr);
    k_part<<<NBLK, 256, 0, stream>>>(ei, bucket_base, bhoff, tmp, flags);
    k_bsort<<<NBUCK, 256, 0, stream>>>(tmp, bucket_base, csr_src, row_ptr, dinv);

    k_gcnt<<<(N_NODES + 256 * GCNT_CHUNK - 1) / (256 * GCNT_CHUNK), 256, 0, stream>>>(bat, gcnt, flags);

    // layer 1: Y1 = X @ W1 ; H = relu(A Y1 + b1)
    k_gemm1<<<N_NODES / 32, 256, 0, stream>>>(x, W1T, Y1, flags);
    k_agg<1><<<N_NODES / 4, 256, 0, stream>>>(Y1, Hb, row_ptr, csr_src, dinv, bc1);

    // layer 2 (aggregate-first): Z = A H ; pooled += relu(Z @ W2 + b2)
    k_agg<0><<<N_NODES / 4, 256, 0, stream>>>(Hb, Zb, row_ptr, csr_src, dinv, nullptr);
    k_gemm2_pool<<<N_NODES / 32, 512, 0, stream>>>(Zb, W2T, bc2, bat, flags, pooled);

    // final FC
    k_final<<<N_GRAPHS, 512, 0, stream>>>(pooled, gcnt, fcWc, fcbc, d_out, flags);
}

// Round 3
// 450.880 us; speedup vs baseline: 1.0630x; 1.0630x over previous
//
#include <hip/hip_runtime.h>
#include <hip/hip_bf16.h>
#include <cstdint>

#define N_NODES 100000
#define N_EDGES 1600000
#define N_GRAPHS 64
#define IN_DIM 256
#define HD1 128
#define HD2 256
#define OUT_DIM 512

// CSR-build radix partition parameters
#define NBUCK 196          // ceil(100000/512) buckets of 512 dst nodes
#define NBLK  196          // edge-chunk blocks
#define EPB   8192         // edges per block (NBLK*EPB >= N_EDGES)

typedef __bf16 bf16x8 __attribute__((ext_vector_type(8)));
typedef float f32x4 __attribute__((ext_vector_type(4)));

static __device__ __forceinline__ float bflo(uint32_t v) { return __uint_as_float(v << 16); }
static __device__ __forceinline__ float bfhi(uint32_t v) { return __uint_as_float(v & 0xffff0000u); }
static __device__ __forceinline__ uint32_t f2bf_bits(float f) {
    uint32_t u = __float_as_uint(f);
    return (u + 0x7fffu + ((u >> 16) & 1u)) >> 16;   // RNE
}
static __device__ __forceinline__ uint32_t packbf(float a, float b) {
    return f2bf_bits(a) | (f2bf_bits(b) << 16);
}
static __device__ __forceinline__ float bf2f(uint16_t b) { return __uint_as_float(((uint32_t)b) << 16); }

// ---------------- runtime dtype probe ----------------
__global__ void k_probe(const uint32_t* __restrict__ xw, const int* __restrict__ ei,
                        int* __restrict__ flags) {
    if (threadIdx.x != 0 || blockIdx.x != 0) return;
    int mid = 0;
    for (int i = 0; i < 64; i++) {
        uint32_t f = (xw[i] >> 23) & 0xFF;
        if (f >= 64 && f < 200) mid++;
    }
    flags[0] = (mid < 32) ? 1 : 0;                  // bf16 vs f32
    int nz = 0;
    for (int i = 0; i < 64; i++) if (ei[2 * i + 1] != 0) nz++;
    flags[1] = (nz == 0) ? 1 : 0;                   // int64 vs int32
}

static __device__ __forceinline__ int ld_idx(const int* p, int i, int sh) { return p[i << sh]; }
static __device__ __forceinline__ float ld_f(const void* p, int i, int isbf) {
    return isbf ? bf2f(((const uint16_t*)p)[i]) : ((const float*)p)[i];
}

// ---------------- fused weight/bias canonicalization (bf16) ----------------
// W1/W2 are packed into per-wave MFMA fragment order so that each B-fragment
// load in the GEMMs is a single fully-coalesced 1KB segment:
//   W1F[(((n0g*8+ks)*2+nt)*64 + lane)*8 + j] = W1[k][n]
//     k = ks*32 + (lane>>4)*8 + j, n = n0g*32 + nt*16 + (lane&15)   (n0g<4, ks<8)
//   W2F[(((n0g*4+ks)*2+nt)*64 + lane)*8 + j] = W2[k][n]
//     k = ks*32 + (lane>>4)*8 + j, n = n0g*32 + nt*16 + (lane&15)   (n0g<8, ks<4)
__global__ __launch_bounds__(256) void k_prep(const void* __restrict__ W1, const void* __restrict__ W2,
                                              const void* __restrict__ fcW, const void* __restrict__ b1,
                                              const void* __restrict__ b2, const void* __restrict__ fcb,
                                              uint16_t* __restrict__ W1F, uint16_t* __restrict__ W2F,
                                              uint16_t* __restrict__ fcWc, uint16_t* __restrict__ bc1,
                                              uint16_t* __restrict__ bc2, uint16_t* __restrict__ fcbc,
                                              const int* __restrict__ flags) {
    int i = blockIdx.x * 256 + threadIdx.x;
    int isbf = flags[0];
    if (i < 32768) {                                   // W1F packed fragments
        int j = i & 7, l = (i >> 3) & 63, nt = (i >> 9) & 1, ks = (i >> 10) & 7, n0g = (i >> 13) & 3;
        int k = ks * 32 + (l >> 4) * 8 + j;
        int n = n0g * 32 + nt * 16 + (l & 15);
        W1F[i] = (uint16_t)f2bf_bits(ld_f(W1, k * HD1 + n, isbf));
    } else if (i < 65536) {                            // W2F packed fragments
        int j2 = i - 32768;
        int j = j2 & 7, l = (j2 >> 3) & 63, nt = (j2 >> 9) & 1, ks = (j2 >> 10) & 3, n0g = (j2 >> 12) & 7;
        int k = ks * 32 + (l >> 4) * 8 + j;
        int n = n0g * 32 + nt * 16 + (l & 15);
        W2F[j2] = (uint16_t)f2bf_bits(ld_f(W2, k * HD2 + n, isbf));
    } else if (i < 196608) {
        int j = i - 65536;
        fcWc[j] = (uint16_t)f2bf_bits(ld_f(fcW, j, isbf));
    } else if (i < 196736) {
        bc1[i - 196608] = (uint16_t)f2bf_bits(ld_f(b1, i - 196608, isbf));
    } else if (i < 196992) {
        bc2[i - 196736] = (uint16_t)f2bf_bits(ld_f(b2, i - 196736, isbf));
    } else if (i < 197504) {
        fcbc[i - 196992] = (uint16_t)f2bf_bits(ld_f(fcb, i - 196992, isbf));
    }
}

// ---------------- CSR build: atomic-free radix partition by dst bucket ----------------

__global__ __launch_bounds__(256) void k_hist(const int* __restrict__ ei, int* __restrict__ bh,
                                              const int* __restrict__ flags) {
    __shared__ int h[NBUCK];
    int t = threadIdx.x, blk = blockIdx.x;
    if (t < NBUCK) h[t] = 0;
    __syncthreads();
    int sh = flags[1];
    int base = blk * EPB;
#pragma unroll
    for (int k = 0; k < EPB / 256; k++) {
        int e = base + k * 256 + t;
        if (e < N_EDGES) atomicAdd(&h[ld_idx(ei, N_EDGES + e, sh) >> 9], 1);
    }
    __syncthreads();
    if (t < NBUCK) bh[blk * NBUCK + t] = h[t];
}

__global__ __launch_bounds__(256) void k_colscan(const int* __restrict__ bh, int* __restrict__ bhoff,
                                                 int* __restrict__ bucket_cnt) {
    __shared__ int s[256];
    int b = blockIdx.x, t = threadIdx.x;
    int v = (t < NBLK) ? bh[t * NBUCK + b] : 0;
    s[t] = v; __syncthreads();
    for (int off = 1; off < 256; off <<= 1) {
        int x = (t >= off) ? s[t - off] : 0;
        __syncthreads();
        s[t] += x;
        __syncthreads();
    }
    if (t < NBLK) bhoff[t * NBUCK + b] = s[t] - v;    // exclusive within bucket
    if (t == 255) bucket_cnt[b] = s[255];
}

__global__ __launch_bounds__(256) void k_bscan(const int* __restrict__ bucket_cnt,
                                               int* __restrict__ bucket_base,
                                               int* __restrict__ row_ptr) {
    __shared__ int s[256];
    int t = threadIdx.x;
    int v = (t < NBUCK) ? bucket_cnt[t] : 0;
    s[t] = v; __syncthreads();
    for (int off = 1; off < 256; off <<= 1) {
        int x = (t >= off) ? s[t - off] : 0;
        __syncthreads();
        s[t] += x;
        __syncthreads();
    }
    if (t < NBUCK) bucket_base[t] = s[t] - v;
    if (t == NBUCK - 1) { bucket_base[NBUCK] = s[t]; row_ptr[N_NODES] = s[t]; }
}

__global__ __launch_bounds__(256) void k_part(const int* __restrict__ ei,
                                              const int* __restrict__ bucket_base,
                                              const int* __restrict__ bhoff,
                                              int* __restrict__ tmp,
                                              const int* __restrict__ flags) {
    __shared__ int cur[NBUCK];
    int t = threadIdx.x, blk = blockIdx.x;
    if (t < NBUCK) cur[t] = bucket_base[t] + bhoff[blk * NBUCK + t];
    __syncthreads();
    int sh = flags[1];
    int base = blk * EPB;
#pragma unroll
    for (int k = 0; k < EPB / 256; k++) {
        int e = base + k * 256 + t;
        if (e < N_EDGES) {
            int s = ld_idx(ei, e, sh), d = ld_idx(ei, N_EDGES + e, sh);
            int pos = atomicAdd(&cur[d >> 9], 1);
            tmp[pos] = (s << 9) | (d & 511);          // s<2^17 -> 26-bit key
        }
    }
}

__global__ __launch_bounds__(256) void k_bsort(const int* __restrict__ tmp,
                                               const int* __restrict__ bucket_base,
                                               int* __restrict__ csr_src,
                                               int* __restrict__ row_ptr,
                                               float* __restrict__ dinv) {
    __shared__ int h[512], a[512], c[512];
    int b = blockIdx.x, t = threadIdx.x;
    int beg = bucket_base[b], end = bucket_base[b + 1];
    h[t] = 0; h[t + 256] = 0;
    __syncthreads();
    for (int i = beg + t; i < end; i += 256) atomicAdd(&h[tmp[i] & 511], 1);
    __syncthreads();
    a[t] = h[t]; a[t + 256] = h[t + 256];
    __syncthreads();
    for (int off = 1; off < 512; off <<= 1) {
        int x0 = (t >= off) ? a[t - off] : 0;
        int x1 = ((t + 256) >= off) ? a[t + 256 - off] : 0;
        __syncthreads();
        a[t] += x0; a[t + 256] += x1;
        __syncthreads();
    }
#pragma unroll
    for (int u = 0; u < 2; u++) {
        int i = t + u * 256;
        int node = (b << 9) + i;
        int ex = a[i] - h[i];
        if (node < N_NODES) {
            row_ptr[node] = beg + ex;
            dinv[node] = rsqrtf((float)(h[i] + 1));   // +1 self-loop
        }
        c[i] = ex;
    }
    __syncthreads();
    for (int i = beg + t; i < end; i += 256) {
        int e = tmp[i];
        int pos = atomicAdd(&c[e & 511], 1);
        csr_src[beg + pos] = e >> 9;
    }
}

// ---------------- per-graph node counts ----------------
#define GCNT_CHUNK 8
__global__ __launch_bounds__(256) void k_gcnt(const int* __restrict__ bat, int* __restrict__ gcnt,
                                              const int* __restrict__ flags) {
    __shared__ int h[N_GRAPHS];
    int t = threadIdx.x;
    if (t < N_GRAPHS) h[t] = 0;
    __syncthreads();
    int sh = flags[1];
    int base = (blockIdx.x * 256 + t) * GCNT_CHUNK;
    int cur = -1, run = 0;
#pragma unroll
    for (int u = 0; u < GCNT_CHUNK; u++) {
        int i = base + u;
        if (i < N_NODES) {
            int g = ld_idx(bat, i, sh);
            if (g == cur) run++;
            else { if (run) atomicAdd(&h[cur], run); cur = g; run = 1; }
        }
    }
    if (run) atomicAdd(&h[cur], run);
    __syncthreads();
    if (t < N_GRAPHS) { int v = h[t]; if (v) atomicAdd(&gcnt[t], v); }
}

// ---------------- GEMM-1: Y1[M,128] = X[M,256] @ W1 ----------------
// Fully register-resident tiles, straight-line load batches:
//  - block = 128 rows x 32 cols; 4 waves own DISTINCT 32-row groups (unique
//    HBM streams -> max unique bytes in flight), all share the same B slice
//    (identical loads -> L1 merge).
//  - B: 16 coalesced 1KB loads from the packed W1F layout.
//  - A: 16 independent 16B/lane loads issued back-to-back BEFORE any MFMA
//    (no launch_bounds cap -> compiler can keep the whole batch live).
// No LDS, no barriers. grid = (4 col-groups, 782 row-blocks), col fastest.

__global__ __launch_bounds__(256) void k_gemm1(const void* __restrict__ Ain,
                                               const uint16_t* __restrict__ BF,  // W1F packed
                                               uint16_t* __restrict__ C,
                                               const int* __restrict__ flags) {
    const int M = N_NODES, K = IN_DIM, N = HD1;
    int isbf = flags[0];
    int t = threadIdx.x;
    int wave = t >> 6, lane = t & 63;
    int quad = lane >> 4, l16 = lane & 15;
    int m0 = blockIdx.y * 128 + wave * 32;
    int n0 = blockIdx.x * 32;

    // B fragments: 16 x 1KB coalesced (L2-hot)
    bf16x8 Bf[8][2];
#pragma unroll
    for (int ks = 0; ks < 8; ks++)
#pragma unroll
        for (int nt = 0; nt < 2; nt++)
            Bf[ks][nt] = *(const bf16x8*)(BF + ((((blockIdx.x * 8 + ks) * 2 + nt) << 6) + lane) * 8);

    int arow[2];
#pragma unroll
    for (int mt = 0; mt < 2; mt++) {
        int r = m0 + mt * 16 + l16;
        arow[mt] = r < M ? r : M - 1;                 // clamp; store guarded
    }

    // A fragments: 16 independent HBM loads, all in flight before use
    bf16x8 Af[8][2];
    if (isbf) {
        const uint16_t* Ab = (const uint16_t*)Ain;
#pragma unroll
        for (int ks = 0; ks < 8; ks++)
#pragma unroll
            for (int mt = 0; mt < 2; mt++)
                Af[ks][mt] = *(const bf16x8*)(Ab + arow[mt] * K + ks * 32 + quad * 8);
    } else {
        const float* Afp = (const float*)Ain;
#pragma unroll
        for (int ks = 0; ks < 8; ks++)
#pragma unroll
            for (int mt = 0; mt < 2; mt++) {
                const float* p = Afp + arow[mt] * K + ks * 32 + quad * 8;
                f32x4 f0 = *(const f32x4*)p, f1 = *(const f32x4*)(p + 4);
                union { uint16_t u[8]; bf16x8 v; } r;
#pragma unroll
                for (int j = 0; j < 4; j++) {
                    r.u[j]     = (uint16_t)f2bf_bits(f0[j]);
                    r.u[4 + j] = (uint16_t)f2bf_bits(f1[j]);
                }
                Af[ks][mt] = r.v;
            }
    }

    f32x4 acc[2][2];
#pragma unroll
    for (int a = 0; a < 2; a++)
#pragma unroll
        for (int b = 0; b < 2; b++) acc[a][b] = f32x4{0.f, 0.f, 0.f, 0.f};

#pragma unroll
    for (int ks = 0; ks < 8; ks++)
#pragma unroll
        for (int mt = 0; mt < 2; mt++)
#pragma unroll
            for (int nt = 0; nt < 2; nt++)
                acc[mt][nt] = __builtin_amdgcn_mfma_f32_16x16x32_bf16(Af[ks][mt], Bf[ks][nt], acc[mt][nt], 0, 0, 0);

#pragma unroll
    for (int mt = 0; mt < 2; mt++)
#pragma unroll
        for (int reg = 0; reg < 4; reg++) {
            int row = m0 + mt * 16 + quad * 4 + reg;  // C/D: col=lane&15, row=quad*4+reg
            if (row < M)
#pragma unroll
                for (int nt = 0; nt < 2; nt++)
                    C[row * N + n0 + nt * 16 + l16] = (uint16_t)f2bf_bits(acc[mt][nt][reg]);
        }
}

// ---------------- aggregation (wave-cooperative; readlane broadcast, 16-deep gather) ----------------
// out[d] = dinv[d] * (sum_src dinv[s]*Y[s] + dinv[d]*Y[d]) [+bias, relu]
// v_readlane (uniform index) -> SGPR src + scalar addressing: no ds_bpermute LDS-pipe traffic.

template <int WITH_BIAS_RELU>
__global__ __launch_bounds__(256) void k_agg(const uint16_t* __restrict__ Yin, uint16_t* __restrict__ Yout,
                                             const int* __restrict__ row_ptr, const int* __restrict__ csr_src,
                                             const float* __restrict__ dinv, const uint16_t* __restrict__ bias) {
    int node = blockIdx.x * 4 + (threadIdx.x >> 6);
    int l = threadIdx.x & 63;
    const uint32_t* Y32 = (const uint32_t*)Yin;

    float wd = dinv[node];
    uint32_t v = Y32[(size_t)node * 64 + l];
    float a0 = wd * bflo(v), a1 = wd * bfhi(v);

    int e0 = row_ptr[node], e1 = row_ptr[node + 1];
    for (int cb = e0; cb < e1; cb += 64) {
        int cnt = e1 - cb; if (cnt > 64) cnt = 64;
        // lane-parallel prefetch of indices + weights (1 coalesced load + 1 gather)
        int my_src = 0; uint32_t my_w = 0;            // lanes >= cnt: w=0 -> contribute 0, read row 0
        if (l < cnt) { my_src = csr_src[cb + l]; my_w = __float_as_uint(dinv[my_src]); }
        int rounds = (cnt + 15) >> 4;
        for (int r = 0; r < rounds; r++) {
            int jb = r * 16;
            uint32_t vv[16];
#pragma unroll
            for (int t = 0; t < 16; t++) {
                int s = __builtin_amdgcn_readlane(my_src, jb + t);   // SGPR: scalar addr math
                vv[t] = Y32[(size_t)s * 64 + l];
            }
#pragma unroll
            for (int t = 0; t < 16; t++) {
                float w = __uint_as_float(__builtin_amdgcn_readlane(my_w, jb + t));
                a0 += w * bflo(vv[t]);
                a1 += w * bfhi(vv[t]);
            }
        }
    }
    a0 *= wd; a1 *= wd;
    if (WITH_BIAS_RELU) {
        a0 = fmaxf(a0 + bf2f(bias[2 * l]), 0.f);
        a1 = fmaxf(a1 + bf2f(bias[2 * l + 1]), 0.f);
    }
    ((uint32_t*)Yout)[(size_t)node * 64 + l] = packbf(a0, a1);
}

// ---------------- GEMM-2 + fused bias/relu/pool: pooled[g] += relu(Z@W2 + b2) ----------------
// Same structure as k_gemm1: block = 128 rows x 32 cols, 4 waves with distinct
// rows, register-resident A (8 loads) and B (8 x 1KB packed loads).

__global__ __launch_bounds__(256) void k_gemm2_pool(const uint16_t* __restrict__ A,   // Zb [M][128]
                                                    const uint16_t* __restrict__ BF,  // W2F packed
                                                    const uint16_t* __restrict__ bias,// bc2 [256]
                                                    const int* __restrict__ bat,
                                                    const int* __restrict__ flags,
                                                    float* __restrict__ pooled) {
    const int M = N_NODES, K = HD1;
    int t = threadIdx.x;
    int wave = t >> 6, lane = t & 63;
    int quad = lane >> 4, l16 = lane & 15;
    int m0 = blockIdx.y * 128 + wave * 32;
    int n0 = blockIdx.x * 32;

    bf16x8 Bf[4][2];
#pragma unroll
    for (int ks = 0; ks < 4; ks++)
#pragma unroll
        for (int nt = 0; nt < 2; nt++)
            Bf[ks][nt] = *(const bf16x8*)(BF + ((((blockIdx.x * 4 + ks) * 2 + nt) << 6) + lane) * 8);

    int arow[2];
#pragma unroll
    for (int mt = 0; mt < 2; mt++) {
        int r = m0 + mt * 16 + l16;
        arow[mt] = r < M ? r : M - 1;
    }

    bf16x8 Af[4][2];
#pragma unroll
    for (int ks = 0; ks < 4; ks++)
#pragma unroll
        for (int mt = 0; mt < 2; mt++)
            Af[ks][mt] = *(const bf16x8*)(A + arow[mt] * K + ks * 32 + quad * 8);

    f32x4 acc[2][2];
#pragma unroll
    for (int a = 0; a < 2; a++)
#pragma unroll
        for (int b = 0; b < 2; b++) acc[a][b] = f32x4{0.f, 0.f, 0.f, 0.f};

#pragma unroll
    for (int ks = 0; ks < 4; ks++)
#pragma unroll
        for (int mt = 0; mt < 2; mt++)
#pragma unroll
            for (int nt = 0; nt < 2; nt++)
                acc[mt][nt] = __builtin_amdgcn_mfma_f32_16x16x32_bf16(Af[ks][mt], Bf[ks][nt], acc[mt][nt], 0, 0, 0);

    int sh = flags[1];
    float bv[2];
#pragma unroll
    for (int nt = 0; nt < 2; nt++) bv[nt] = bf2f(bias[n0 + nt * 16 + l16]);

    // M % 32 == 0 -> a wave's 32 rows are all-valid or all-invalid.
    if (m0 < M) {
        int gfirst = ld_idx(bat, m0, sh);
        int glast  = ld_idx(bat, m0 + 31, sh);
        if (gfirst == glast) {
#pragma unroll
            for (int nt = 0; nt < 2; nt++) {
                float s = 0.f;
#pragma unroll
                for (int mt = 0; mt < 2; mt++)
#pragma unroll
                    for (int reg = 0; reg < 4; reg++)
                        s += fmaxf(acc[mt][nt][reg] + bv[nt], 0.f);
                s += __shfl_xor(s, 16);
                s += __shfl_xor(s, 32);
                if (quad == 0)
                    atomicAdd(&pooled[gfirst * HD2 + n0 + nt * 16 + l16], s);
            }
        } else {
#pragma unroll
            for (int mt = 0; mt < 2; mt++) {
                int rb = m0 + mt * 16 + quad * 4;
#pragma unroll
                for (int reg = 0; reg < 4; reg++) {
                    int g = ld_idx(bat, rb + reg, sh);
#pragma unroll
                    for (int nt = 0; nt < 2; nt++)
                        atomicAdd(&pooled[g * HD2 + n0 + nt * 16 + l16],
                                  fmaxf(acc[mt][nt][reg] + bv[nt], 0.f));
                }
            }
        }
    }
}

// ---------------- final FC: out = relu(mean @ fcW + fcb), dual-dtype out ----------------

__global__ __launch_bounds__(512) void k_final(const float* __restrict__ pooled, const int* __restrict__ gcnt,
                                               const uint16_t* __restrict__ fcWc, const uint16_t* __restrict__ fcbc,
                                               void* __restrict__ out, const int* __restrict__ flags) {
    __shared__ float pm[HD2];
    int g = blockIdx.x, t = threadIdx.x;
    if (t < HD2) pm[t] = pooled[g * HD2 + t] / fmaxf((float)gcnt[g], 1.0f);
    __syncthreads();
    float acc = bf2f(fcbc[t]);
    for (int k = 0; k < HD2; k++) acc = fmaf(pm[k], bf2f(fcWc[k * OUT_DIM + t]), acc);
    acc = fmaxf(acc, 0.f);
    if (flags[0]) ((uint16_t*)out)[g * OUT_DIM + t] = (uint16_t)f2bf_bits(acc);
    else          ((float*)out)[g * OUT_DIM + t] = acc;
}

// ---------------- launcher ----------------

extern "C" void kernel_launch(void* const* d_in, const int* in_sizes, int n_in,
                              void* d_out, int out_size, void* d_ws, size_t ws_size,
                              hipStream_t stream) {
    const void* x   = d_in[0];               // [100000,256] bf16 or f32
    const int*  ei  = (const int*)d_in[1];   // [2,1600000] int32 or int64
    const int*  bat = (const int*)d_in[2];   // [100000]
    const void* W1  = d_in[3];               // [256,128]
    const void* b1  = d_in[4];               // [128]
    const void* W2  = d_in[5];               // [128,256]
    const void* b2  = d_in[6];               // [256]
    const void* fcW = d_in[7];               // [256,512]
    const void* fcb = d_in[8];               // [512]

    char* ws = (char*)d_ws;
    size_t off = 0;
    auto alloc = [&](size_t bytes) -> void* {
        void* p = ws + off;
        off += (bytes + 255) & ~(size_t)255;
        return p;
    };
    uint16_t* buf0 = (uint16_t*)alloc((size_t)N_NODES * HD1 * 2);   // Y1, later Zb
    uint16_t* Hb   = (uint16_t*)alloc((size_t)N_NODES * HD1 * 2);
    int*   row_ptr = (int*)alloc((N_NODES + 1) * 4);
    int*   csr_src = (int*)alloc((size_t)N_EDGES * 4);
    int*   tmp     = (int*)alloc((size_t)N_EDGES * 4);
    int*   bh      = (int*)alloc(NBLK * NBUCK * 4);
    int*   bhoff   = (int*)alloc(NBLK * NBUCK * 4);
    int*   bucket_cnt  = (int*)alloc(NBUCK * 4);
    int*   bucket_base = (int*)alloc((NBUCK + 1) * 4);
    float* dinv    = (float*)alloc(N_NODES * 4);
    int*   gcnt    = (int*)alloc(N_GRAPHS * 4);
    float* pooled  = (float*)alloc(N_GRAPHS * HD2 * 4);
    uint16_t* W1T  = (uint16_t*)alloc(IN_DIM * HD1 * 2);
    uint16_t* W2T  = (uint16_t*)alloc(HD1 * HD2 * 2);
    uint16_t* bc1  = (uint16_t*)alloc(HD1 * 2);
    uint16_t* bc2  = (uint16_t*)alloc(HD2 * 2);
    uint16_t* fcWc = (uint16_t*)alloc(HD2 * OUT_DIM * 2);
    uint16_t* fcbc = (uint16_t*)alloc(OUT_DIM * 2);
    int*   flags   = (int*)alloc(64 * 4);

    uint16_t* Y1 = buf0;
    uint16_t* Zb = buf0;   // Y1 dead after agg-1

    hipMemsetAsync(gcnt, 0, N_GRAPHS * 4, stream);
    hipMemsetAsync(pooled, 0, N_GRAPHS * HD2 * 4, stream);

    k_probe<<<1, 64, 0, stream>>>((const uint32_t*)x, ei, flags);

    // canonicalize weights/biases to bf16 (one fused kernel; W1/W2 fragment-packed)
    k_prep<<<(197504 + 255) / 256, 256, 0, stream>>>(W1, W2, fcW, b1, b2, fcb,
                                                     W1T, W2T, fcWc, bc1, bc2, fcbc, flags);

    // CSR build: hist -> colscan -> bscan -> part -> bucket sort (no global atomics)
    k_hist<<<NBLK, 256, 0, stream>>>(ei, bh, flags);
    k_colscan<<<NBUCK, 256, 0, stream>>>(bh, bhoff, bucket_cnt);
    k_bscan<<<1, 256, 0, stream>>>(bucket_cnt, bucket_base, row_ptr);
    k_part<<<NBLK, 256, 0, stream>>>(ei, bucket_base, bhoff, tmp, flags);
    k_bsort<<<NBUCK, 256, 0, stream>>>(tmp, bucket_base, csr_src, row_ptr, dinv);

    k_gcnt<<<(N_NODES + 256 * GCNT_CHUNK - 1) / (256 * GCNT_CHUNK), 256, 0, stream>>>(bat, gcnt, flags);

    // layer 1: Y1 = X @ W1 ; H = relu(A Y1 + b1)
    k_gemm1<<<dim3(4, (N_NODES + 127) / 128), 256, 0, stream>>>(x, W1T, Y1, flags);
    k_agg<1><<<N_NODES / 4, 256, 0, stream>>>(Y1, Hb, row_ptr, csr_src, dinv, bc1);

    // layer 2 (aggregate-first): Z = A H ; pooled += relu(Z @ W2 + b2)
    k_agg<0><<<N_NODES / 4, 256, 0, stream>>>(Hb, Zb, row_ptr, csr_src, dinv, nullptr);
    k_gemm2_pool<<<dim3(8, (N_NODES + 127) / 128), 256, 0, stream>>>(Zb, W2T, bc2, bat, flags, pooled);

    // final FC
    k_final<<<N_GRAPHS, 512, 0, stream>>>(pooled, gcnt, fcWc, fcbc, d_out, flags);
}

// Round 5
// 417.769 us; speedup vs baseline: 1.1473x; 1.0793x over previous
//
#include <hip/hip_runtime.h>
#include <hip/hip_bf16.h>
#include <cstdint>

#define N_NODES 100000
#define N_EDGES 1600000
#define N_GRAPHS 64
#define IN_DIM 256
#define HD1 128
#define HD2 256
#define OUT_DIM 512

// CSR-build radix partition parameters
#define NBUCK 196          // ceil(100000/512) buckets of 512 dst nodes
#define NBLK  196          // edge-chunk blocks
#define EPB   8192         // edges per block (NBLK*EPB >= N_EDGES)

typedef __bf16 bf16x8 __attribute__((ext_vector_type(8)));
typedef float f32x4 __attribute__((ext_vector_type(4)));

static __device__ __forceinline__ float bflo(uint32_t v) { return __uint_as_float(v << 16); }
static __device__ __forceinline__ float bfhi(uint32_t v) { return __uint_as_float(v & 0xffff0000u); }
static __device__ __forceinline__ uint32_t f2bf_bits(float f) {
    uint32_t u = __float_as_uint(f);
    return (u + 0x7fffu + ((u >> 16) & 1u)) >> 16;   // RNE
}
static __device__ __forceinline__ uint32_t packbf(float a, float b) {
    return f2bf_bits(a) | (f2bf_bits(b) << 16);
}
static __device__ __forceinline__ float bf2f(uint16_t b) { return __uint_as_float(((uint32_t)b) << 16); }

// direct global->LDS 16B copy (no VGPR round-trip); lds dest is wave-uniform
// base + lane*16 (we pass the per-lane address; HW takes lane0's base).
static __device__ __forceinline__ void gl_lds16(const void* g, void* l) {
    __builtin_amdgcn_global_load_lds((const __attribute__((address_space(1))) uint32_t*)g,
                                     (__attribute__((address_space(3))) uint32_t*)l, 16, 0, 0);
}

// ---------------- runtime dtype probe ----------------
__global__ void k_probe(const uint32_t* __restrict__ xw, const int* __restrict__ ei,
                        int* __restrict__ flags) {
    if (threadIdx.x != 0 || blockIdx.x != 0) return;
    int mid = 0;
    for (int i = 0; i < 64; i++) {
        uint32_t f = (xw[i] >> 23) & 0xFF;
        if (f >= 64 && f < 200) mid++;
    }
    flags[0] = (mid < 32) ? 1 : 0;                  // bf16 vs f32
    int nz = 0;
    for (int i = 0; i < 64; i++) if (ei[2 * i + 1] != 0) nz++;
    flags[1] = (nz == 0) ? 1 : 0;                   // int64 vs int32
}

static __device__ __forceinline__ int ld_idx(const int* p, int i, int sh) { return p[i << sh]; }
static __device__ __forceinline__ float ld_f(const void* p, int i, int isbf) {
    return isbf ? bf2f(((const uint16_t*)p)[i]) : ((const float*)p)[i];
}

// ---------------- fused weight/bias canonicalization (bf16) ----------------
// W1/W2 packed into per-wave MFMA fragment order: each B-fragment load in the
// GEMMs is a single fully-coalesced 1KB segment (L2-hot, shared by all blocks):
//   W1F[(((n0g*8+ks)*2+nt)*64 + lane)*8 + j] = W1[k][n]
//     k = ks*32 + (lane>>4)*8 + j, n = n0g*32 + nt*16 + (lane&15)   (n0g<4, ks<8)
//   W2F[(((n0g*4+ks)*2+nt)*64 + lane)*8 + j] = W2[k][n]
//     k = ks*32 + (lane>>4)*8 + j, n = n0g*32 + nt*16 + (lane&15)   (n0g<8, ks<4)
__global__ __launch_bounds__(256) void k_prep(const void* __restrict__ W1, const void* __restrict__ W2,
                                              const void* __restrict__ fcW, const void* __restrict__ b1,
                                              const void* __restrict__ b2, const void* __restrict__ fcb,
                                              uint16_t* __restrict__ W1F, uint16_t* __restrict__ W2F,
                                              uint16_t* __restrict__ fcWc, uint16_t* __restrict__ bc1,
                                              uint16_t* __restrict__ bc2, uint16_t* __restrict__ fcbc,
                                              const int* __restrict__ flags) {
    int i = blockIdx.x * 256 + threadIdx.x;
    int isbf = flags[0];
    if (i < 32768) {                                   // W1F packed fragments
        int j = i & 7, l = (i >> 3) & 63, nt = (i >> 9) & 1, ks = (i >> 10) & 7, n0g = (i >> 13) & 3;
        int k = ks * 32 + (l >> 4) * 8 + j;
        int n = n0g * 32 + nt * 16 + (l & 15);
        W1F[i] = (uint16_t)f2bf_bits(ld_f(W1, k * HD1 + n, isbf));
    } else if (i < 65536) {                            // W2F packed fragments
        int j2 = i - 32768;
        int j = j2 & 7, l = (j2 >> 3) & 63, nt = (j2 >> 9) & 1, ks = (j2 >> 10) & 3, n0g = (j2 >> 12) & 7;
        int k = ks * 32 + (l >> 4) * 8 + j;
        int n = n0g * 32 + nt * 16 + (l & 15);
        W2F[j2] = (uint16_t)f2bf_bits(ld_f(W2, k * HD2 + n, isbf));
    } else if (i < 196608) {
        int j = i - 65536;
        fcWc[j] = (uint16_t)f2bf_bits(ld_f(fcW, j, isbf));
    } else if (i < 196736) {
        bc1[i - 196608] = (uint16_t)f2bf_bits(ld_f(b1, i - 196608, isbf));
    } else if (i < 196992) {
        bc2[i - 196736] = (uint16_t)f2bf_bits(ld_f(b2, i - 196736, isbf));
    } else if (i < 197504) {
        fcbc[i - 196992] = (uint16_t)f2bf_bits(ld_f(fcb, i - 196992, isbf));
    }
}

// ---------------- CSR build: atomic-free radix partition by dst bucket ----------------

__global__ __launch_bounds__(256) void k_hist(const int* __restrict__ ei, int* __restrict__ bh,
                                              const int* __restrict__ flags) {
    __shared__ int h[NBUCK];
    int t = threadIdx.x, blk = blockIdx.x;
    if (t < NBUCK) h[t] = 0;
    __syncthreads();
    int sh = flags[1];
    int base = blk * EPB;
#pragma unroll
    for (int k = 0; k < EPB / 256; k++) {
        int e = base + k * 256 + t;
        if (e < N_EDGES) atomicAdd(&h[ld_idx(ei, N_EDGES + e, sh) >> 9], 1);
    }
    __syncthreads();
    if (t < NBUCK) bh[blk * NBUCK + t] = h[t];
}

__global__ __launch_bounds__(256) void k_colscan(const int* __restrict__ bh, int* __restrict__ bhoff,
                                                 int* __restrict__ bucket_cnt) {
    __shared__ int s[256];
    int b = blockIdx.x, t = threadIdx.x;
    int v = (t < NBLK) ? bh[t * NBUCK + b] : 0;
    s[t] = v; __syncthreads();
    for (int off = 1; off < 256; off <<= 1) {
        int x = (t >= off) ? s[t - off] : 0;
        __syncthreads();
        s[t] += x;
        __syncthreads();
    }
    if (t < NBLK) bhoff[t * NBUCK + b] = s[t] - v;    // exclusive within bucket
    if (t == 255) bucket_cnt[b] = s[255];
}

__global__ __launch_bounds__(256) void k_bscan(const int* __restrict__ bucket_cnt,
                                               int* __restrict__ bucket_base,
                                               int* __restrict__ row_ptr) {
    __shared__ int s[256];
    int t = threadIdx.x;
    int v = (t < NBUCK) ? bucket_cnt[t] : 0;
    s[t] = v; __syncthreads();
    for (int off = 1; off < 256; off <<= 1) {
        int x = (t >= off) ? s[t - off] : 0;
        __syncthreads();
        s[t] += x;
        __syncthreads();
    }
    if (t < NBUCK) bucket_base[t] = s[t] - v;
    if (t == NBUCK - 1) { bucket_base[NBUCK] = s[t]; row_ptr[N_NODES] = s[t]; }
}

__global__ __launch_bounds__(256) void k_part(const int* __restrict__ ei,
                                              const int* __restrict__ bucket_base,
                                              const int* __restrict__ bhoff,
                                              int* __restrict__ tmp,
                                              const int* __restrict__ flags) {
    __shared__ int cur[NBUCK];
    int t = threadIdx.x, blk = blockIdx.x;
    if (t < NBUCK) cur[t] = bucket_base[t] + bhoff[blk * NBUCK + t];
    __syncthreads();
    int sh = flags[1];
    int base = blk * EPB;
#pragma unroll
    for (int k = 0; k < EPB / 256; k++) {
        int e = base + k * 256 + t;
        if (e < N_EDGES) {
            int s = ld_idx(ei, e, sh), d = ld_idx(ei, N_EDGES + e, sh);
            int pos = atomicAdd(&cur[d >> 9], 1);
            tmp[pos] = (s << 9) | (d & 511);          // s<2^17 -> 26-bit key
        }
    }
}

__global__ __launch_bounds__(256) void k_bsort(const int* __restrict__ tmp,
                                               const int* __restrict__ bucket_base,
                                               int* __restrict__ csr_src,
                                               int* __restrict__ row_ptr,
                                               float* __restrict__ dinv) {
    __shared__ int h[512], a[512], c[512];
    int b = blockIdx.x, t = threadIdx.x;
    int beg = bucket_base[b], end = bucket_base[b + 1];
    h[t] = 0; h[t + 256] = 0;
    __syncthreads();
    for (int i = beg + t; i < end; i += 256) atomicAdd(&h[tmp[i] & 511], 1);
    __syncthreads();
    a[t] = h[t]; a[t + 256] = h[t + 256];
    __syncthreads();
    for (int off = 1; off < 512; off <<= 1) {
        int x0 = (t >= off) ? a[t - off] : 0;
        int x1 = ((t + 256) >= off) ? a[t + 256 - off] : 0;
        __syncthreads();
        a[t] += x0; a[t + 256] += x1;
        __syncthreads();
    }
#pragma unroll
    for (int u = 0; u < 2; u++) {
        int i = t + u * 256;
        int node = (b << 9) + i;
        int ex = a[i] - h[i];
        if (node < N_NODES) {
            row_ptr[node] = beg + ex;
            dinv[node] = rsqrtf((float)(h[i] + 1));   // +1 self-loop
        }
        c[i] = ex;
    }
    __syncthreads();
    for (int i = beg + t; i < end; i += 256) {
        int e = tmp[i];
        int pos = atomicAdd(&c[e & 511], 1);
        csr_src[beg + pos] = e >> 9;
    }
}

// ---------------- per-graph node counts ----------------
#define GCNT_CHUNK 8
__global__ __launch_bounds__(256) void k_gcnt(const int* __restrict__ bat, int* __restrict__ gcnt,
                                              const int* __restrict__ flags) {
    __shared__ int h[N_GRAPHS];
    int t = threadIdx.x;
    if (t < N_GRAPHS) h[t] = 0;
    __syncthreads();
    int sh = flags[1];
    int base = (blockIdx.x * 256 + t) * GCNT_CHUNK;
    int cur = -1, run = 0;
#pragma unroll
    for (int u = 0; u < GCNT_CHUNK; u++) {
        int i = base + u;
        if (i < N_NODES) {
            int g = ld_idx(bat, i, sh);
            if (g == cur) run++;
            else { if (run) atomicAdd(&h[cur], run); cur = g; run = 1; }
        }
    }
    if (run) atomicAdd(&h[cur], run);
    __syncthreads();
    if (t < N_GRAPHS) { int v = h[t]; if (v) atomicAdd(&gcnt[t], v); }
}

// ---------------- GEMM-1: Y1[M,128] = X[M,256] @ W1 ----------------
// Block = 64 rows x FULL 128 cols (A read exactly once -> FETCH = ideal).
// A: one-shot global_load_lds stage (no VGPR round-trip), XOR-swizzled via
// pre-swizzled SOURCE address (linear LDS dest; rule: both-sides-or-neither).
// B: per-wave 32 cols register-resident, 16 x 1KB coalesced packed loads.
// One barrier total; stage latency hidden by 3+ independent blocks/CU.

__global__ __launch_bounds__(256) void k_gemm1(const void* __restrict__ Ain,
                                               const uint16_t* __restrict__ BF,  // W1F packed
                                               uint16_t* __restrict__ C,
                                               const int* __restrict__ flags) {
    __shared__ __align__(16) uint16_t As[64 * 256];   // 32 KB, swizzled, 16B-aligned
    const int M = N_NODES, N = HD1;
    int isbf = flags[0];
    int t = threadIdx.x;
    int wave = t >> 6, lane = t & 63;
    int quad = lane >> 4, l16 = lane & 15;
    int m0 = blockIdx.x * 64;
    int n0 = wave * 32;                               // wave's col group (n0g = wave)

    // B fragments: 16 x 1KB coalesced (L2-hot), issued before the stage
    bf16x8 Bf[8][2];
#pragma unroll
    for (int ks = 0; ks < 8; ks++)
#pragma unroll
        for (int nt = 0; nt < 2; nt++)
            Bf[ks][nt] = *(const bf16x8*)(BF + ((((wave * 8 + ks) * 2 + nt) << 6) + lane) * 8);

    // A-tile stage: 32 KB = 8 x (256 threads x 16B). LDS byte o holds logical
    // (r, c) with c = (o&511) ^ ((r&7)<<4)  -> read side applies the same XOR.
    if (isbf) {
        const uint8_t* Xb = (const uint8_t*)Ain;
#pragma unroll
        for (int i = 0; i < 8; i++) {
            int o = (i * 256 + t) * 16;
            int r = o >> 9, c = o & 511;
            int rg = m0 + r; if (rg >= M) rg = M - 1;
            gl_lds16(Xb + (size_t)rg * 512 + (c ^ ((r & 7) << 4)), (uint8_t*)As + o);
        }
    } else {
        const float* Xf = (const float*)Ain;
#pragma unroll
        for (int i = 0; i < 8; i++) {
            int o = (i * 256 + t) * 16;
            int r = o >> 9, c = (o & 511) ^ ((r & 7) << 4);
            int rg = m0 + r; if (rg >= M) rg = M - 1;
            const float* p = Xf + (size_t)rg * 256 + (c >> 1);
            f32x4 f0 = *(const f32x4*)p, f1 = *(const f32x4*)(p + 4);
            union { uint16_t u[8]; bf16x8 v; } rr;
#pragma unroll
            for (int j = 0; j < 4; j++) {
                rr.u[j]     = (uint16_t)f2bf_bits(f0[j]);
                rr.u[4 + j] = (uint16_t)f2bf_bits(f1[j]);
            }
            *(bf16x8*)((uint8_t*)As + o) = rr.v;
        }
    }
    __syncthreads();

    f32x4 acc[4][2];
#pragma unroll
    for (int a = 0; a < 4; a++)
#pragma unroll
        for (int b = 0; b < 2; b++) acc[a][b] = f32x4{0.f, 0.f, 0.f, 0.f};

#pragma unroll
    for (int ks = 0; ks < 8; ks++) {
        bf16x8 af[4];
#pragma unroll
        for (int mt = 0; mt < 4; mt++) {
            int r = mt * 16 + l16;
            int cb = (ks * 64 + quad * 16) ^ ((r & 7) << 4);
            af[mt] = *(const bf16x8*)((const uint8_t*)As + r * 512 + cb);
        }
#pragma unroll
        for (int mt = 0; mt < 4; mt++)
#pragma unroll
            for (int nt = 0; nt < 2; nt++)
                acc[mt][nt] = __builtin_amdgcn_mfma_f32_16x16x32_bf16(af[mt], Bf[ks][nt], acc[mt][nt], 0, 0, 0);
    }

#pragma unroll
    for (int mt = 0; mt < 4; mt++)
#pragma unroll
        for (int reg = 0; reg < 4; reg++) {
            int row = m0 + mt * 16 + quad * 4 + reg;  // C/D: col=lane&15, row=quad*4+reg
            if (row < M)
#pragma unroll
                for (int nt = 0; nt < 2; nt++)
                    C[row * N + n0 + nt * 16 + l16] = (uint16_t)f2bf_bits(acc[mt][nt][reg]);
        }
}

// ---------------- aggregation (wave-cooperative; readlane broadcast, 16-deep gather) ----------------
// out[d] = dinv[d] * (sum_src dinv[s]*Y[s] + dinv[d]*Y[d]) [+bias, relu]
// v_readlane (uniform index) -> SGPR src + scalar addressing: no ds_bpermute LDS-pipe traffic.

template <int WITH_BIAS_RELU>
__global__ __launch_bounds__(256) void k_agg(const uint16_t* __restrict__ Yin, uint16_t* __restrict__ Yout,
                                             const int* __restrict__ row_ptr, const int* __restrict__ csr_src,
                                             const float* __restrict__ dinv, const uint16_t* __restrict__ bias) {
    int node = blockIdx.x * 4 + (threadIdx.x >> 6);
    int l = threadIdx.x & 63;
    const uint32_t* Y32 = (const uint32_t*)Yin;

    float wd = dinv[node];
    uint32_t v = Y32[(size_t)node * 64 + l];
    float a0 = wd * bflo(v), a1 = wd * bfhi(v);

    int e0 = row_ptr[node], e1 = row_ptr[node + 1];
    for (int cb = e0; cb < e1; cb += 64) {
        int cnt = e1 - cb; if (cnt > 64) cnt = 64;
        // lane-parallel prefetch of indices + weights (1 coalesced load + 1 gather)
        int my_src = 0; uint32_t my_w = 0;            // lanes >= cnt: w=0 -> contribute 0, read row 0
        if (l < cnt) { my_src = csr_src[cb + l]; my_w = __float_as_uint(dinv[my_src]); }
        int rounds = (cnt + 15) >> 4;
        for (int r = 0; r < rounds; r++) {
            int jb = r * 16;
            uint32_t vv[16];
#pragma unroll
            for (int t = 0; t < 16; t++) {
                int s = __builtin_amdgcn_readlane(my_src, jb + t);   // SGPR: scalar addr math
                vv[t] = Y32[(size_t)s * 64 + l];
            }
#pragma unroll
            for (int t = 0; t < 16; t++) {
                float w = __uint_as_float(__builtin_amdgcn_readlane(my_w, jb + t));
                a0 += w * bflo(vv[t]);
                a1 += w * bfhi(vv[t]);
            }
        }
    }
    a0 *= wd; a1 *= wd;
    if (WITH_BIAS_RELU) {
        a0 = fmaxf(a0 + bf2f(bias[2 * l]), 0.f);
        a1 = fmaxf(a1 + bf2f(bias[2 * l + 1]), 0.f);
    }
    ((uint32_t*)Yout)[(size_t)node * 64 + l] = packbf(a0, a1);
}

// ---------------- GEMM-2 + fused bias/relu/pool: pooled[g] += relu(Z@W2 + b2) ----------------
// Same structure as k_gemm1: block = 64 rows x FULL 256 cols (A staged once),
// 8 waves x 32 cols, register-resident packed B, swizzled LDS A-tile.

__global__ __launch_bounds__(512) void k_gemm2_pool(const uint16_t* __restrict__ A,   // Zb [M][128]
                                                    const uint16_t* __restrict__ BF,  // W2F packed
                                                    const uint16_t* __restrict__ bias,// bc2 [256]
                                                    const int* __restrict__ bat,
                                                    const int* __restrict__ flags,
                                                    float* __restrict__ pooled) {
    __shared__ __align__(16) uint16_t As[64 * 128];   // 16 KB, swizzled, 16B-aligned
    const int M = N_NODES;
    int t = threadIdx.x;
    int wave = t >> 6, lane = t & 63;
    int quad = lane >> 4, l16 = lane & 15;
    int m0 = blockIdx.x * 64;
    int n0 = wave * 32;                               // 8 waves x 32 cols = 256

    bf16x8 Bf[4][2];
#pragma unroll
    for (int ks = 0; ks < 4; ks++)
#pragma unroll
        for (int nt = 0; nt < 2; nt++)
            Bf[ks][nt] = *(const bf16x8*)(BF + ((((wave * 4 + ks) * 2 + nt) << 6) + lane) * 8);

    // A-tile stage: 16 KB = 2 x (512 threads x 16B); Zb is always bf16
#pragma unroll
    for (int i = 0; i < 2; i++) {
        int o = (i * 512 + t) * 16;
        int r = o >> 8, c = o & 255;
        int rg = m0 + r; if (rg >= M) rg = M - 1;
        gl_lds16((const uint8_t*)A + (size_t)rg * 256 + (c ^ ((r & 7) << 4)), (uint8_t*)As + o);
    }
    __syncthreads();

    f32x4 acc[4][2];
#pragma unroll
    for (int a = 0; a < 4; a++)
#pragma unroll
        for (int b = 0; b < 2; b++) acc[a][b] = f32x4{0.f, 0.f, 0.f, 0.f};

#pragma unroll
    for (int ks = 0; ks < 4; ks++) {
        bf16x8 af[4];
#pragma unroll
        for (int mt = 0; mt < 4; mt++) {
            int r = mt * 16 + l16;
            int cb = (ks * 64 + quad * 16) ^ ((r & 7) << 4);
            af[mt] = *(const bf16x8*)((const uint8_t*)As + r * 256 + cb);
        }
#pragma unroll
        for (int mt = 0; mt < 4; mt++)
#pragma unroll
            for (int nt = 0; nt < 2; nt++)
                acc[mt][nt] = __builtin_amdgcn_mfma_f32_16x16x32_bf16(af[mt], Bf[ks][nt], acc[mt][nt], 0, 0, 0);
    }

    int sh = flags[1];
    float bv[2];
#pragma unroll
    for (int nt = 0; nt < 2; nt++) bv[nt] = bf2f(bias[n0 + nt * 16 + l16]);

    int last = m0 + 63 < M ? m0 + 63 : M - 1;
    int gfirst = ld_idx(bat, m0, sh);
    int glast  = ld_idx(bat, last, sh);
    if ((m0 + 63 < M) && gfirst == glast) {
        // all 64 rows valid, same graph: wave-local reduction, 1 atomic/col
#pragma unroll
        for (int nt = 0; nt < 2; nt++) {
            float s = 0.f;
#pragma unroll
            for (int mt = 0; mt < 4; mt++)
#pragma unroll
                for (int reg = 0; reg < 4; reg++)
                    s += fmaxf(acc[mt][nt][reg] + bv[nt], 0.f);
            s += __shfl_xor(s, 16);
            s += __shfl_xor(s, 32);
            if (quad == 0)
                atomicAdd(&pooled[gfirst * HD2 + n0 + nt * 16 + l16], s);
        }
    } else {
#pragma unroll
        for (int mt = 0; mt < 4; mt++) {
#pragma unroll
            for (int reg = 0; reg < 4; reg++) {
                int row = m0 + mt * 16 + quad * 4 + reg;
                if (row < M) {
                    int g = ld_idx(bat, row, sh);
#pragma unroll
                    for (int nt = 0; nt < 2; nt++)
                        atomicAdd(&pooled[g * HD2 + n0 + nt * 16 + l16],
                                  fmaxf(acc[mt][nt][reg] + bv[nt], 0.f));
                }
            }
        }
    }
}

// ---------------- final FC: out = relu(mean @ fcW + fcb), dual-dtype out ----------------

__global__ __launch_bounds__(512) void k_final(const float* __restrict__ pooled, const int* __restrict__ gcnt,
                                               const uint16_t* __restrict__ fcWc, const uint16_t* __restrict__ fcbc,
                                               void* __restrict__ out, const int* __restrict__ flags) {
    __shared__ float pm[HD2];
    int g = blockIdx.x, t = threadIdx.x;
    if (t < HD2) pm[t] = pooled[g * HD2 + t] / fmaxf((float)gcnt[g], 1.0f);
    __syncthreads();
    float acc = bf2f(fcbc[t]);
    for (int k = 0; k < HD2; k++) acc = fmaf(pm[k], bf2f(fcWc[k * OUT_DIM + t]), acc);
    acc = fmaxf(acc, 0.f);
    if (flags[0]) ((uint16_t*)out)[g * OUT_DIM + t] = (uint16_t)f2bf_bits(acc);
    else          ((float*)out)[g * OUT_DIM + t] = acc;
}

// ---------------- launcher ----------------

extern "C" void kernel_launch(void* const* d_in, const int* in_sizes, int n_in,
                              void* d_out, int out_size, void* d_ws, size_t ws_size,
                              hipStream_t stream) {
    const void* x   = d_in[0];               // [100000,256] bf16 or f32
    const int*  ei  = (const int*)d_in[1];   // [2,1600000] int32 or int64
    const int*  bat = (const int*)d_in[2];   // [100000]
    const void* W1  = d_in[3];               // [256,128]
    const void* b1  = d_in[4];               // [128]
    const void* W2  = d_in[5];               // [128,256]
    const void* b2  = d_in[6];               // [256]
    const void* fcW = d_in[7];               // [256,512]
    const void* fcb = d_in[8];               // [512]

    char* ws = (char*)d_ws;
    size_t off = 0;
    auto alloc = [&](size_t bytes) -> void* {
        void* p = ws + off;
        off += (bytes + 255) & ~(size_t)255;
        return p;
    };
    uint16_t* buf0 = (uint16_t*)alloc((size_t)N_NODES * HD1 * 2);   // Y1, later Zb
    uint16_t* Hb   = (uint16_t*)alloc((size_t)N_NODES * HD1 * 2);
    int*   row_ptr = (int*)alloc((N_NODES + 1) * 4);
    int*   csr_src = (int*)alloc((size_t)N_EDGES * 4);
    int*   tmp     = (int*)alloc((size_t)N_EDGES * 4);
    int*   bh      = (int*)alloc(NBLK * NBUCK * 4);
    int*   bhoff   = (int*)alloc(NBLK * NBUCK * 4);
    int*   bucket_cnt  = (int*)alloc(NBUCK * 4);
    int*   bucket_base = (int*)alloc((NBUCK + 1) * 4);
    float* dinv    = (float*)alloc(N_NODES * 4);
    int*   gcnt    = (int*)alloc(N_GRAPHS * 4);
    float* pooled  = (float*)alloc(N_GRAPHS * HD2 * 4);
    uint16_t* W1T  = (uint16_t*)alloc(IN_DIM * HD1 * 2);
    uint16_t* W2T  = (uint16_t*)alloc(HD1 * HD2 * 2);
    uint16_t* bc1  = (uint16_t*)alloc(HD1 * 2);
    uint16_t* bc2  = (uint16_t*)alloc(HD2 * 2);
    uint16_t* fcWc = (uint16_t*)alloc(HD2 * OUT_DIM * 2);
    uint16_t* fcbc = (uint16_t*)alloc(OUT_DIM * 2);
    int*   flags   = (int*)alloc(64 * 4);

    uint16_t* Y1 = buf0;
    uint16_t* Zb = buf0;   // Y1 dead after agg-1

    hipMemsetAsync(gcnt, 0, N_GRAPHS * 4, stream);
    hipMemsetAsync(pooled, 0, N_GRAPHS * HD2 * 4, stream);

    k_probe<<<1, 64, 0, stream>>>((const uint32_t*)x, ei, flags);

    // canonicalize weights/biases to bf16 (one fused kernel; W1/W2 fragment-packed)
    k_prep<<<(197504 + 255) / 256, 256, 0, stream>>>(W1, W2, fcW, b1, b2, fcb,
                                                     W1T, W2T, fcWc, bc1, bc2, fcbc, flags);

    // CSR build: hist -> colscan -> bscan -> part -> bucket sort (no global atomics)
    k_hist<<<NBLK, 256, 0, stream>>>(ei, bh, flags);
    k_colscan<<<NBUCK, 256, 0, stream>>>(bh, bhoff, bucket_cnt);
    k_bscan<<<1, 256, 0, stream>>>(bucket_cnt, bucket_base, row_ptr);
    k_part<<<NBLK, 256, 0, stream>>>(ei, bucket_base, bhoff, tmp, flags);
    k_bsort<<<NBUCK, 256, 0, stream>>>(tmp, bucket_base, csr_src, row_ptr, dinv);

    k_gcnt<<<(N_NODES + 256 * GCNT_CHUNK - 1) / (256 * GCNT_CHUNK), 256, 0, stream>>>(bat, gcnt, flags);

    // layer 1: Y1 = X @ W1 ; H = relu(A Y1 + b1)
    k_gemm1<<<(N_NODES + 63) / 64, 256, 0, stream>>>(x, W1T, Y1, flags);
    k_agg<1><<<N_NODES / 4, 256, 0, stream>>>(Y1, Hb, row_ptr, csr_src, dinv, bc1);

    // layer 2 (aggregate-first): Z = A H ; pooled += relu(Z @ W2 + b2)
    k_agg<0><<<N_NODES / 4, 256, 0, stream>>>(Hb, Zb, row_ptr, csr_src, dinv, nullptr);
    k_gemm2_pool<<<(N_NODES + 63) / 64, 512, 0, stream>>>(Zb, W2T, bc2, bat, flags, pooled);

    // final FC
    k_final<<<N_GRAPHS, 512, 0, stream>>>(pooled, gcnt, fcWc, fcbc, d_out, flags);
}